// Round 2
// baseline (145.151 us; speedup 1.0000x reference)
//
#include <hip/hip_runtime.h>
#include <cstdint>

// FlexAttention (sliding-window causal + per-head sink), R11.
// B=2,H=16,S=2048,D=64,W=1024.
//
// R11 = R10 with the two failure-risk mechanisms fixed:
//  1. glds16 uses REAL addrspacecasts (AS1/AS3 pointer casts), not integer
//     truncation, for __builtin_amdgcn_global_load_lds.
//  2. KV bf16 swizzled images live in d_out (exactly out_size = 16 MB);
//     OUT is dead during main since ALL items route through combine.
//     WS holds only partials: 43 slots/bh x 16KB + m/l = 23.95 MB, under
//     the 26.7 MB proven-safe (R9) workspace footprint.
// Structure: prep converts K/V fp32->bf16 swizzled LDS images once;
// main stages tiles via 4x global_load_lds(16B) (no kreg/vreg, no cvt or
// ds_write staging VALU, no staging bank conflicts); __launch_bounds__(256,4)
// with 32-bin/bh schedule (grid 1024 = 4 blocks/CU, 16 waves/CU).
// LDS 32 KB (2x8K K + 2x8K V), one barrier/tile, glds prefetch issued
// right after the barrier into the just-freed buffer.
// Layouts (m74/m101): A[m=l&31][k=(l>>5)*8+j], B[k=..][n=l&31],
// C/D[row=(rg&3)+8*(rg>>2)+4*(l>>5)][col=l&31].

typedef __bf16 bf16x8 __attribute__((ext_vector_type(8)));
typedef __bf16 bf16x4 __attribute__((ext_vector_type(4)));
typedef float  f32x16 __attribute__((ext_vector_type(16)));

#define NT 256
#define NEG_BIG (-3.0e38f)

typedef const __attribute__((address_space(1))) void gvoid;
typedef __attribute__((address_space(3))) void lvoid;

__device__ __forceinline__ void glds16(const void* g, void* l) {
    __builtin_amdgcn_global_load_lds((gvoid*)g, (lvoid*)l, 16, 0, 0);
}

__device__ __forceinline__ int swz(int row, int gran) {
    return row * 64 + ((gran ^ ((row >> 1) & 7)) << 3);
}

__device__ __forceinline__ bf16x4 xswap32(bf16x4 v) {
    union { bf16x4 v; int i[2]; } u;
    u.v = v;
    u.i[0] = __shfl_xor(u.i[0], 32, 64);
    u.i[1] = __shfl_xor(u.i[1], 32, 64);
    return u.v;
}

// ---- baked schedule: 32 bins/bh, 24x7 + 8x6 = 216 tiles, <=2 segs/bin ----
__device__ const int SEG_N[32] = {
  2,1,1,2,2,1,2,1, 2,1,2,1,1,2,1,1, 1,1,2,1,1,2,1,1, 1,1,2,1,1,2,1,1};
__device__ const int SEG_IT[32][2] = {
  {0,1},{2,0},{3,0},{3,4},{4,5},{5,0},{5,6},{6,0},
  {6,7},{7,0},{7,8},{8,0},{8,0},{8,9},{9,0},{9,0},
  {10,0},{10,0},{10,11},{11,0},{11,0},{11,12},{12,0},{12,0},
  {13,0},{13,0},{13,14},{14,0},{14,0},{14,15},{15,0},{15,0}};
__device__ const int SEG_J0[32][2] = {
  {0,0},{0,0},{0,0},{7,0},{6,0},{3,0},{10,0},{5,0},
  {12,0},{5,0},{12,0},{2,0},{9,0},{16,0},{5,0},{12,0},
  {0,0},{7,0},{14,0},{3,0},{10,0},{17,0},{6,0},{12,0},
  {0,0},{7,0},{14,0},{3,0},{10,0},{17,0},{6,0},{12,0}};
__device__ const int SEG_J1[32][2] = {
  {2,4},{6,0},{7,0},{8,6},{10,3},{10,0},{12,5},{12,0},
  {14,5},{12,0},{16,2},{9,0},{16,0},{18,5},{12,0},{18,0},
  {7,0},{14,0},{18,3},{10,0},{17,0},{18,6},{12,0},{18,0},
  {7,0},{14,0},{18,3},{10,0},{17,0},{18,6},{12,0},{18,0}};
__device__ const int SEG_SX[32][2] = {
  {0,0},{0,0},{0,0},{1,0},{1,0},{1,0},{2,0},{1,0},
  {2,0},{1,0},{2,0},{1,0},{2,0},{3,0},{1,0},{2,0},
  {0,0},{1,0},{2,0},{1,0},{2,0},{3,0},{1,0},{2,0},
  {0,0},{1,0},{2,0},{1,0},{2,0},{3,0},{1,0},{2,0}};
// segments per item (ALL items go through combine now)
__device__ const int NSEG16[16]      = {1,1,1,2,2,3,3,3,4,3,3,4,3,3,4,3};
// compact partial-slot base per item (43 slots/bh total)
__device__ const int SLOT_BASE16[16] = {0,1,2,3,5,7,10,13,16,20,23,26,30,33,36,40};
#define NSLOT 43

// ---- pre-pass: K/V fp32 -> bf16 swizzled LDS images, stored in OUT ----
__global__ __launch_bounds__(256) void flex_r11_prep(
    const float* __restrict__ K, const float* __restrict__ V,
    float* __restrict__ IMG, const int H, const int S)
{
    const int t  = threadIdx.x;
    const int bh = blockIdx.x >> 5;
    const int kt = blockIdx.x & 31;
    const size_t basebh = (size_t)bh * S * 64;
    const float4* kp4 = (const float4*)(K + basebh);
    const float4* vp4 = (const float4*)(V + basebh);
    __bf16* img = (__bf16*)IMG + ((size_t)bh * 32 + kt) * 8192;

    // K image: identical layout math to R9's in-kernel staging
    #pragma unroll
    for (int i = 0; i < 4; ++i) {
        const int flat = i * 256 + t;
        const int key = flat >> 4, dd = flat & 15;
        float4 f = kp4[kt * 1024 + flat];
        bf16x4 b = { (__bf16)f.x, (__bf16)f.y, (__bf16)f.z, (__bf16)f.w };
        *(bf16x4*)&img[swz(key, dd >> 1) + (dd & 1) * 4] = b;
    }
    // V image (transposed): dims 4dgi..+3, keys 4kgi..+3
    const int dgi = t & 15, kgi = t >> 4;
    float4 a0 = vp4[kt * 1024 + (4 * kgi + 0) * 16 + dgi];
    float4 a1 = vp4[kt * 1024 + (4 * kgi + 1) * 16 + dgi];
    float4 a2 = vp4[kt * 1024 + (4 * kgi + 2) * 16 + dgi];
    float4 a3 = vp4[kt * 1024 + (4 * kgi + 3) * 16 + dgi];
    bf16x4 w0 = { (__bf16)a0.x, (__bf16)a1.x, (__bf16)a2.x, (__bf16)a3.x };
    bf16x4 w1 = { (__bf16)a0.y, (__bf16)a1.y, (__bf16)a2.y, (__bf16)a3.y };
    bf16x4 w2 = { (__bf16)a0.z, (__bf16)a1.z, (__bf16)a2.z, (__bf16)a3.z };
    bf16x4 w3 = { (__bf16)a0.w, (__bf16)a1.w, (__bf16)a2.w, (__bf16)a3.w };
    const int gv = kgi >> 1, ov = (kgi & 1) * 4;
    __bf16* imgV = img + 4096;
    *(bf16x4*)&imgV[swz(4 * dgi + 0, gv) + ov] = w0;
    *(bf16x4*)&imgV[swz(4 * dgi + 1, gv) + ov] = w1;
    *(bf16x4*)&imgV[swz(4 * dgi + 2, gv) + ov] = w2;
    *(bf16x4*)&imgV[swz(4 * dgi + 3, gv) + ov] = w3;
}

__global__ __launch_bounds__(NT, 4) void flex_r11_main(
    const float* __restrict__ Q, const float* __restrict__ SINKW,
    const int* __restrict__ SWIN, void* __restrict__ WS,
    const float* __restrict__ IMG, const int H, const int S)
{
    const int t    = threadIdx.x;
    const int lane = t & 63;
    const int w    = t >> 6;
    const int c    = lane & 31;
    const int hl   = lane >> 5;
    const int W    = SWIN[0];
    const float scale = 0.125f;

    const int NBH = gridDim.x / 32;
    const int bh  = blockIdx.x / 32;
    const int bin = blockIdx.x - bh * 32;
    const int h   = bh % H;
    const float sw = SINKW[h];

    __shared__ __align__(16) __bf16 k_lds[2][64 * 64];
    __shared__ __align__(16) __bf16 v_lds[2][64 * 64];

    const size_t basebh = (size_t)bh * S * 64;
    const __bf16* kvimg = (const __bf16*)IMG + (size_t)bh * 32 * 8192;
    __bf16* O_ws  = (__bf16*)WS;
    float2* ml_ws = (float2*)((char*)WS + (size_t)NBH * NSLOT * 16384);

    const int wb = (t >> 6) << 10;   // wave-uniform LDS byte base
    const int ns = SEG_N[bin];

    // ---- prologue: stage first tile into buffer 0 via global_load_lds ----
    {
        const int it0  = SEG_IT[bin][0];
        const int ktA0 = (2 * it0 - 16 > 0) ? (2 * it0 - 16) : 0;
        const int kt   = ktA0 + SEG_J0[bin][0];
        const char* g  = (const char*)(kvimg + (size_t)kt * 8192);
        char* lk = (char*)&k_lds[0][0];
        char* lv = (char*)&v_lds[0][0];
        glds16(g +         t * 16, lk + wb);
        glds16(g +  4096 + t * 16, lk + wb + 4096);
        glds16(g +  8192 + t * 16, lv + wb);
        glds16(g + 12288 + t * 16, lv + wb + 4096);
    }

    int par = 0;

    for (int s = 0; s < ns; ++s) {
        const int item = SEG_IT[bin][s];
        const int j0   = SEG_J0[bin][s];
        const int j1   = SEG_J1[bin][s];
        const int sidx = SEG_SX[bin][s];
        const int ktA  = (2 * item - 16 > 0) ? (2 * item - 16) : 0;
        const int qw0  = item * 128 + 32 * w;
        const int qi   = qw0 + c;

        // ---- Q B-fragments (pre-scaled) ----
        bf16x8 bq[4];
        {
            const float4* qp4 = (const float4*)(Q + basebh + (size_t)qi * 64);
            #pragma unroll
            for (int ks = 0; ks < 4; ++ks) {
                float4 f0 = qp4[4 * ks + 2 * hl];
                float4 f1 = qp4[4 * ks + 2 * hl + 1];
                bq[ks][0] = (__bf16)(f0.x * scale); bq[ks][1] = (__bf16)(f0.y * scale);
                bq[ks][2] = (__bf16)(f0.z * scale); bq[ks][3] = (__bf16)(f0.w * scale);
                bq[ks][4] = (__bf16)(f1.x * scale); bq[ks][5] = (__bf16)(f1.y * scale);
                bq[ks][6] = (__bf16)(f1.z * scale); bq[ks][7] = (__bf16)(f1.w * scale);
            }
        }

        float mrun = (sidx == 0) ? sw : NEG_BIG;
        float lrun = (sidx == 0) ? 1.0f : 0.0f;
        f32x16 accO0, accO1;
        #pragma unroll
        for (int i = 0; i < 16; ++i) { accO0[i] = 0.0f; accO1[i] = 0.0f; }

        for (int j = j0; j < j1; ++j) {
            const int k0 = (ktA + j) * 64;

            __syncthreads();   // buf[par] landed (vmcnt drain); prev reads done

            // ---- prefetch next tile into the just-freed buffer ----
            int nkt = -1;
            if (j + 1 < j1) nkt = ktA + j + 1;
            else if (s + 1 < ns) {
                const int it2  = SEG_IT[bin][s + 1];
                const int ktA2 = (2 * it2 - 16 > 0) ? (2 * it2 - 16) : 0;
                nkt = ktA2 + SEG_J0[bin][s + 1];
            }
            if (nkt >= 0) {
                const int np = par ^ 1;
                const char* g = (const char*)(kvimg + (size_t)nkt * 8192);
                char* lk = (char*)&k_lds[np][0];
                char* lv = (char*)&v_lds[np][0];
                glds16(g +         t * 16, lk + wb);
                glds16(g +  4096 + t * 16, lk + wb + 4096);
                glds16(g +  8192 + t * 16, lv + wb);
                glds16(g + 12288 + t * 16, lv + wb + 4096);
            }

            // ---- S^T = K · Q^T ----
            const __bf16* kb = k_lds[par];
            const __bf16* vb = v_lds[par];
            f32x16 accS0, accS1;
            #pragma unroll
            for (int i = 0; i < 16; ++i) { accS0[i] = 0.0f; accS1[i] = 0.0f; }
            #pragma unroll
            for (int ks = 0; ks < 4; ++ks) {
                bf16x8 ka0 = *(const bf16x8*)&kb[swz(c,      2 * ks + hl)];
                bf16x8 ka1 = *(const bf16x8*)&kb[swz(32 + c, 2 * ks + hl)];
                accS0 = __builtin_amdgcn_mfma_f32_32x32x16_bf16(ka0, bq[ks], accS0, 0, 0, 0);
                accS1 = __builtin_amdgcn_mfma_f32_32x32x16_bf16(ka1, bq[ks], accS1, 0, 0, 0);
            }

            // ---- mask (wave-uniform skip when interior) ----
            const bool interior = (k0 + 63 <= qw0) && (qw0 + 31 - k0 <= W);
            if (!interior) {
                #pragma unroll
                for (int rg = 0; rg < 16; ++rg) {
                    const int kb2 = (rg & 3) + 8 * (rg >> 2) + 4 * hl;
                    const int ki0 = k0 + kb2, ki1 = k0 + 32 + kb2;
                    if (!((ki0 <= qi) && (qi - ki0 <= W))) accS0[rg] = -1e30f;
                    if (!((ki1 <= qi) && (qi - ki1 <= W))) accS1[rg] = -1e30f;
                }
            }

            // ---- online softmax ----
            float mx = accS0[0];
            #pragma unroll
            for (int i = 1; i < 16; ++i) mx = fmaxf(mx, accS0[i]);
            #pragma unroll
            for (int i = 0; i < 16; ++i) mx = fmaxf(mx, accS1[i]);
            mx = fmaxf(mx, __shfl_xor(mx, 32, 64));
            const float mnew  = fmaxf(mrun, mx);
            const float alpha = __expf(mrun - mnew);
            float ps = 0.0f;
            #pragma unroll
            for (int i = 0; i < 16; ++i) { float p = __expf(accS0[i] - mnew); accS0[i] = p; ps += p; }
            #pragma unroll
            for (int i = 0; i < 16; ++i) { float p = __expf(accS1[i] - mnew); accS1[i] = p; ps += p; }
            ps += __shfl_xor(ps, 32, 64);
            lrun = lrun * alpha + ps;
            mrun = mnew;
            #pragma unroll
            for (int i = 0; i < 16; ++i) { accO0[i] *= alpha; accO1[i] *= alpha; }

            // ---- P -> B-fragments IN REGISTERS (half-wave quad exchange) ----
            bf16x4 qA = { (__bf16)accS0[0],  (__bf16)accS0[1],  (__bf16)accS0[2],  (__bf16)accS0[3]  };
            bf16x4 qB = { (__bf16)accS0[4],  (__bf16)accS0[5],  (__bf16)accS0[6],  (__bf16)accS0[7]  };
            bf16x4 qC = { (__bf16)accS0[8],  (__bf16)accS0[9],  (__bf16)accS0[10], (__bf16)accS0[11] };
            bf16x4 qD = { (__bf16)accS0[12], (__bf16)accS0[13], (__bf16)accS0[14], (__bf16)accS0[15] };
            bf16x4 qE = { (__bf16)accS1[0],  (__bf16)accS1[1],  (__bf16)accS1[2],  (__bf16)accS1[3]  };
            bf16x4 qF = { (__bf16)accS1[4],  (__bf16)accS1[5],  (__bf16)accS1[6],  (__bf16)accS1[7]  };
            bf16x4 qG = { (__bf16)accS1[8],  (__bf16)accS1[9],  (__bf16)accS1[10], (__bf16)accS1[11] };
            bf16x4 qH = { (__bf16)accS1[12], (__bf16)accS1[13], (__bf16)accS1[14], (__bf16)accS1[15] };
            bf16x4 r0 = xswap32(hl ? qA : qB);
            bf16x4 r1 = xswap32(hl ? qC : qD);
            bf16x4 r2 = xswap32(hl ? qE : qF);
            bf16x4 r3 = xswap32(hl ? qG : qH);
            bf16x4 lo0 = hl ? r0 : qA, hi0 = hl ? qB : r0;
            bf16x4 lo1 = hl ? r1 : qC, hi1 = hl ? qD : r1;
            bf16x4 lo2 = hl ? r2 : qE, hi2 = hl ? qF : r2;
            bf16x4 lo3 = hl ? r3 : qG, hi3 = hl ? qH : r3;
            bf16x8 bp[4];
            #pragma unroll
            for (int e = 0; e < 4; ++e) {
                bp[0][e] = lo0[e]; bp[0][4+e] = hi0[e];
                bp[1][e] = lo1[e]; bp[1][4+e] = hi1[e];
                bp[2][e] = lo2[e]; bp[2][4+e] = hi2[e];
                bp[3][e] = lo3[e]; bp[3][4+e] = hi3[e];
            }

            // ---- O^T += V^T · P^T ----
            #pragma unroll
            for (int ks = 0; ks < 4; ++ks) {
                bf16x8 va0 = *(const bf16x8*)&vb[swz(c,      2 * ks + hl)];
                bf16x8 va1 = *(const bf16x8*)&vb[swz(32 + c, 2 * ks + hl)];
                accO0 = __builtin_amdgcn_mfma_f32_32x32x16_bf16(va0, bp[ks], accO0, 0, 0, 0);
                accO1 = __builtin_amdgcn_mfma_f32_32x32x16_bf16(va1, bp[ks], accO1, 0, 0, 0);
            }

            par ^= 1;
        }

        // ---- write partials (compact slots, up to 4 per item) ----
        const int slot = bh * NSLOT + SLOT_BASE16[item] + sidx;
        const int qrel = 32 * w + c;
        if (hl == 0) ml_ws[(size_t)slot * 128 + qrel] = make_float2(mrun, lrun);
        __bf16* Os = O_ws + (size_t)slot * 8192 + (size_t)qrel * 64;
        #pragma unroll
        for (int qd = 0; qd < 4; ++qd) {
            const int d0 = 8 * qd + 4 * hl;
            bf16x4 b0 = { (__bf16)accO0[4*qd+0], (__bf16)accO0[4*qd+1],
                          (__bf16)accO0[4*qd+2], (__bf16)accO0[4*qd+3] };
            bf16x4 b1 = { (__bf16)accO1[4*qd+0], (__bf16)accO1[4*qd+1],
                          (__bf16)accO1[4*qd+2], (__bf16)accO1[4*qd+3] };
            *(bf16x4*)&Os[d0]      = b0;
            *(bf16x4*)&Os[32 + d0] = b1;
        }
    }
}

__global__ __launch_bounds__(256) void flex_r11_combine(
    const void* __restrict__ WS, float* __restrict__ OUT, const int H, const int S)
{
    const int NBH  = gridDim.x / 16;
    const int bi   = blockIdx.x;
    const int bh   = bi >> 4;
    const int item = bi & 15;
    const int ns   = NSEG16[item];
    const int t    = threadIdx.x;
    const int q    = t >> 1;
    const int half = t & 1;

    const __bf16* O_ws  = (const __bf16*)WS;
    const float2* ml_ws = (const float2*)((const char*)WS + (size_t)NBH * NSLOT * 16384);
    const int base = bh * NSLOT + SLOT_BASE16[item];

    float m[4], lv[4], a[4];
    float mst = NEG_BIG;
    for (int s = 0; s < ns; ++s) {
        float2 e = ml_ws[(size_t)(base + s) * 128 + q];
        m[s] = e.x; lv[s] = e.y;
        mst = fmaxf(mst, m[s]);
    }
    float lst = 0.0f;
    for (int s = 0; s < ns; ++s) { a[s] = __expf(m[s] - mst); lst += a[s] * lv[s]; }
    const float inv = 1.0f / lst;

    float acc[32];
    #pragma unroll
    for (int i = 0; i < 32; ++i) acc[i] = 0.0f;
    for (int s = 0; s < ns; ++s) {
        const __bf16* Os = O_ws + (size_t)(base + s) * 8192 + (size_t)q * 64 + 32 * half;
        const float as = a[s];
        #pragma unroll
        for (int v8 = 0; v8 < 4; ++v8) {
            bf16x8 o = *(const bf16x8*)&Os[8 * v8];
            #pragma unroll
            for (int jj = 0; jj < 8; ++jj) acc[8 * v8 + jj] += as * (float)o[jj];
        }
    }

    float* dst = OUT + (size_t)bh * S * 64 + (size_t)(item * 128 + q) * 64 + 32 * half;
    #pragma unroll
    for (int v4 = 0; v4 < 8; ++v4) {
        float4 f = { acc[4*v4+0] * inv, acc[4*v4+1] * inv,
                     acc[4*v4+2] * inv, acc[4*v4+3] * inv };
        *(float4*)&dst[4 * v4] = f;
    }
}

extern "C" void kernel_launch(void* const* d_in, const int* in_sizes, int n_in,
                              void* d_out, int out_size, void* d_ws, size_t ws_size,
                              hipStream_t stream) {
    const float* q     = (const float*)d_in[0];
    const float* k     = (const float*)d_in[1];
    const float* v     = (const float*)d_in[2];
    const float* sinkw = (const float*)d_in[3];
    const int*   swin  = (const int*)d_in[4];
    float* out = (float*)d_out;

    const int H = in_sizes[3];                   // 16
    const int S = 2048;
    const int B = in_sizes[0] / (H * S * 64);    // 2
    const int NBH = B * H;                       // 32

    // KV images live in d_out (NBH*32*16384 B == out_size exactly);
    // WS: NBH*43*16384 (partial O, bf16) + NBH*43*1024 (m/l) ~= 23.95 MB.
    flex_r11_prep<<<dim3(NBH * 32), 256, 0, stream>>>(k, v, out, H, S);
    flex_r11_main<<<dim3(NBH * 32), NT, 0, stream>>>(q, sinkw, swin, d_ws, out, H, S);
    flex_r11_combine<<<dim3(NBH * 16), 256, 0, stream>>>(d_ws, out, H, S);
}